// Round 6
// baseline (233.247 us; speedup 1.0000x reference)
//
#include <hip/hip_runtime.h>
#include <math.h>

// ModifiedAttention bf16-MFMA pipeline v6: B=4,S=1024,D=768,H=24,DH=64,DG=1
//  - attn: S^T = K*Q^T operand swap => P exits QK in exactly the A-operand
//    layout of 16x16x16 MFMA; PV feeds from REGISTERS (no P LDS round trip).
//    exp2 with log2e folded into q scale; kg as float4; XCD-stable grid (h,b,pr).
//  - qkv: 8-row supertile block swizzle for wT L2 reuse.
//  - all staging global_load_lds 16B wave-uniform + XOR swizzle.

namespace {

typedef short bf16x8 __attribute__((ext_vector_type(8)));
typedef short bf16x4 __attribute__((ext_vector_type(4)));
typedef float f32x4 __attribute__((ext_vector_type(4)));
typedef unsigned short u16;
typedef u16 u16x8 __attribute__((ext_vector_type(8)));
typedef unsigned int u32;

constexpr int BB = 4, SS = 1024, DD = 768, HH = 24;
constexpr int RR = BB * SS;     // 4096
constexpr int NC = HH * 64;     // 1536
constexpr int NQKV = 3 * NC;    // 4608
constexpr int NTOT = NQKV + 128; // + gate block

__device__ inline u16 f2bf(float f) {   // RNE fp32 -> bf16
    u32 u = __float_as_uint(f);
    u += 0x7FFFu + ((u >> 16) & 1u);
    return (u16)(u >> 16);
}

// async global->LDS, 16B/lane; LDS base MUST be wave-uniform (HW scatters lane*16)
__device__ __forceinline__ void async16(const void* g, const void* lds) {
    __builtin_amdgcn_global_load_lds(
        (const __attribute__((address_space(1))) u32*)(unsigned long long)(size_t)g,
        (__attribute__((address_space(3))) u32*)(u32)(size_t)lds, 16, 0, 0);
}

// ---------------- weight column/row inverse norms ----------------
__global__ __launch_bounds__(256)
void norms_kernel(const float* __restrict__ Wv, const float* __restrict__ Wo,
                  float* __restrict__ invV, float* __restrict__ invO) {
    int j = blockIdx.x;            // (h,dh) flat, 1536
    int h = j >> 6, dh = j & 63;
    __shared__ float sv[256], so[256];
    float av = 0.f, ao = 0.f;
    for (int d = threadIdx.x; d < DD; d += 256) {
        float a = Wv[(h * DD + d) * 64 + dh];    // W_V[h,d,dh], norm over d
        av += a * a;
        float b = Wo[(size_t)j * DD + d];        // W_O[h,dh,d], norm over d
        ao += b * b;
    }
    sv[threadIdx.x] = av; so[threadIdx.x] = ao;
    __syncthreads();
    for (int s = 128; s > 0; s >>= 1) {
        if (threadIdx.x < s) {
            sv[threadIdx.x] += sv[threadIdx.x + s];
            so[threadIdx.x] += so[threadIdx.x + s];
        }
        __syncthreads();
    }
    if (threadIdx.x == 0) {
        invV[j] = 1.f / fmaxf(sqrtf(sv[0]), 1e-12f);
        invO[j] = 1.f / fmaxf(sqrtf(so[0]), 1e-12f);
    }
}

// ---------------- x -> bf16 ----------------
__global__ __launch_bounds__(256)
void x2bf_kernel(const float* __restrict__ x, u16* __restrict__ xb) {
    int idx = blockIdx.x * 256 + threadIdx.x;       // RR*DD/4 float4s
    float4 v = ((const float4*)x)[idx];
    ushort4 o;
    o.x = f2bf(v.x); o.y = f2bf(v.y); o.z = f2bf(v.z); o.w = f2bf(v.w);
    ((ushort4*)xb)[idx] = o;
}

// ---------------- pack W_{Q,K,V} -> wT rows [0,4608) x 768 bf16 ----------------
__global__ __launch_bounds__(256)
void pack_wqkv_kernel(const float* __restrict__ Wq, const float* __restrict__ Wk,
                      const float* __restrict__ Wv, const float* __restrict__ invV,
                      u16* __restrict__ wT) {
    const int k0 = blockIdx.x * 64, h = blockIdx.y, p = blockIdx.z;
    const float* W = (p == 0 ? Wq : p == 1 ? Wk : Wv) + (size_t)h * DD * 64;
    __shared__ float sT[64][68];
    const int t = threadIdx.x;
#pragma unroll
    for (int rep = 0; rep < 4; rep++) {
        int idx = t + rep * 256; int kk = idx >> 4, c = idx & 15;
        *(float4*)&sT[kk][c * 4] = *(const float4*)&W[(size_t)(k0 + kk) * 64 + c * 4];
    }
    __syncthreads();
#pragma unroll
    for (int rep = 0; rep < 2; rep++) {
        int idx = t + rep * 256; int dh = idx >> 3, cj = idx & 7;
        float sc = (p == 2) ? invV[h * 64 + dh] : 1.f;
        u16x8 o;
#pragma unroll
        for (int i = 0; i < 8; i++) o[i] = f2bf(sT[cj * 8 + i][dh] * sc);
        *(u16x8*)&wT[(size_t)(p * NC + h * 64 + dh) * DD + k0 + cj * 8] = o;
    }
}

// ---------------- pack gate weights -> wT rows [4608,4736) ----------------
__global__ __launch_bounds__(256)
void pack_gates_kernel(const float* __restrict__ Wgq, const float* __restrict__ Wgk,
                       u16* __restrict__ wT) {
    int g = blockIdx.x;           // 0..127
    u16* dst = wT + (size_t)(NQKV + g) * DD;
    if (g < 48) {
        const float* src = ((g & 1) ? Wgk : Wgq) + (size_t)(g >> 1) * DD;
        for (int c = threadIdx.x; c < DD; c += 256) dst[c] = f2bf(src[c]);
    } else {
        for (int c = threadIdx.x; c < DD; c += 256) dst[c] = 0;
    }
}

__global__ void pack_bias_kernel(const float* __restrict__ bq, const float* __restrict__ bk,
                                 const float* __restrict__ bv, float* __restrict__ biasp) {
    int n = blockIdx.x * 256 + threadIdx.x;
    if (n >= NQKV) return;
    int p = n / NC, rem = n % NC;
    biasp[n] = (p == 0) ? bq[rem] : (p == 1) ? bk[rem] : bv[rem];
}

// ---------------- pack W_O -> woT [768 d][1536 j] bf16 ----------------
__global__ __launch_bounds__(256)
void pack_wo_kernel(const float* __restrict__ Wo, u16* __restrict__ woT) {
    const int j0 = blockIdx.x * 64, d0 = blockIdx.y * 64;
    __shared__ float sT[64][68];
    const int t = threadIdx.x;
#pragma unroll
    for (int rep = 0; rep < 4; rep++) {
        int idx = t + rep * 256; int jj = idx >> 4, c = idx & 15;
        *(float4*)&sT[jj][c * 4] = *(const float4*)&Wo[(size_t)(j0 + jj) * DD + d0 + c * 4];
    }
    __syncthreads();
#pragma unroll
    for (int rep = 0; rep < 2; rep++) {
        int idx = t + rep * 256; int dd = idx >> 3, cj = idx & 7;
        u16x8 o;
#pragma unroll
        for (int i = 0; i < 8; i++) o[i] = f2bf(sT[cj * 8 + i][dd]);
        *(u16x8*)&woT[(size_t)(d0 + dd) * NC + j0 + cj * 8] = o;
    }
}

// ---------------- qkv+gates MFMA GEMM: C[4096,4736] = xb @ wT^T ----------------
// Supertile swizzle: groups of 8 row-tiles x 37 n-tiles so wT (7.3MB) is
// streamed 4x instead of 32x (L2/L3 reuse).
__global__ __launch_bounds__(256)
void qkv_gemm_kernel(const u16* __restrict__ xb, const u16* __restrict__ wT,
                     const float* __restrict__ biasp,
                     const float* __restrict__ bgq, const float* __restrict__ bgk,
                     u16* __restrict__ qo, u16* __restrict__ ko, u16* __restrict__ vto,
                     float* __restrict__ qgo, float* __restrict__ kgo) {
    const int flat = blockIdx.x + 37 * blockIdx.y;
    const int grp = flat / 296;            // 296 = 8 m-tiles * 37 n-tiles
    const int rem = flat - grp * 296;
    const int row0 = (grp * 8 + (rem & 7)) * 128;
    const int n0 = (rem >> 3) * 128;
    const int t = threadIdx.x, w = t >> 6, l = t & 63, lr = l & 15, lq = l >> 4;
    const int wr = (w >> 1) * 64, wc = (w & 1) * 64;
    __shared__ u16 smem[4 * 4608];   // main: sA 16KB | sB 16KB; epi: 4x 64x72
    u16* sA = smem;
    u16* sB = smem + 8192;

    const int src_row = l >> 3;            // 0..7 within 8-row chunk
    const int cbs = (l & 7) ^ src_row;     // swizzled source col-block
    const int swz = lr & 7;                // read-side swizzle

    f32x4 acc[4][4] = {};
    for (int k0 = 0; k0 < DD; k0 += 64) {
        __syncthreads();
#pragma unroll
        for (int i = 0; i < 4; i++) {
            int ch = w * 4 + i;            // 16 chunks of 8 rows each
            int rowA = ch * 8 + src_row;
            async16(xb + (size_t)(row0 + rowA) * DD + k0 + cbs * 8, sA + ch * 512);
            async16(wT + (size_t)(n0 + rowA) * DD + k0 + cbs * 8, sB + ch * 512);
        }
        __syncthreads();
#pragma unroll
        for (int s = 0; s < 2; s++) {
            const int j8 = ((s * 4 + lq) ^ swz) * 8;
            bf16x8 af[4], bf[4];
#pragma unroll
            for (int i = 0; i < 4; i++) {
                af[i] = *(const bf16x8*)&sA[(wr + i * 16 + lr) * 64 + j8];
                bf[i] = *(const bf16x8*)&sB[(wc + i * 16 + lr) * 64 + j8];
            }
#pragma unroll
            for (int mt = 0; mt < 4; mt++)
#pragma unroll
                for (int nt = 0; nt < 4; nt++)
                    acc[mt][nt] = __builtin_amdgcn_mfma_f32_16x16x32_bf16(
                        af[mt], bf[nt], acc[mt][nt], 0, 0, 0);
        }
    }
    __syncthreads();                       // frag reads done before LDS reuse

    const int p = n0 / NC;                 // 0..3 (3 = gate block)
    const int b = row0 >> 10, s0 = row0 & (SS - 1);

    if (p == 3) {                          // gates: cols j = nt*16+lr < 48
        if (wc == 0) {
#pragma unroll
            for (int nt = 0; nt < 3; nt++) {
                int j = nt * 16 + lr, hh = j >> 1;
                float bias = (j & 1) ? bgk[hh] : bgq[hh];
                float* dst = (j & 1) ? kgo : qgo;
#pragma unroll
                for (int mt = 0; mt < 4; mt++)
#pragma unroll
                    for (int r = 0; r < 4; r++)
                        dst[((size_t)b * HH + hh) * SS + s0 + wr + mt * 16 + lq * 4 + r] =
                            acc[mt][nt][r] + bias;
            }
        }
        return;
    }

    const int cq = n0 + wc, srow = s0 + wr;
    u16* tw = smem + w * 4608;             // per-wave 64 x 72 region
    float bb[4];
#pragma unroll
    for (int nt = 0; nt < 4; nt++) bb[nt] = biasp[cq + nt * 16 + lr];

    if (p < 2) {                           // q or k: layout [s][dh]
        // q: fold 1/sqrt(64) * log2(e) so attention uses raw exp2
        const float sc = (p == 0) ? 0.18033688f : 1.f;
#pragma unroll
        for (int mt = 0; mt < 4; mt++)
#pragma unroll
            for (int nt = 0; nt < 4; nt++)
#pragma unroll
                for (int r = 0; r < 4; r++)
                    tw[(mt * 16 + lq * 4 + r) * 72 + nt * 16 + lr] =
                        f2bf((acc[mt][nt][r] + bb[nt]) * sc);
        const int h = (cq - p * NC) >> 6;
        u16* dst = (p == 0 ? qo : ko) + ((size_t)(b * HH + h) * SS + srow) * 64;
#pragma unroll
        for (int c = 0; c < 8; c++)
            *(u16x8*)&dst[(size_t)l * 64 + c * 8] = *(const u16x8*)&tw[l * 72 + c * 8];
    } else {                               // v: transpose to [dh][s]
#pragma unroll
        for (int mt = 0; mt < 4; mt++)
#pragma unroll
            for (int nt = 0; nt < 4; nt++)
#pragma unroll
                for (int r = 0; r < 4; r++)
                    tw[(nt * 16 + lr) * 72 + mt * 16 + lq * 4 + r] =
                        f2bf(acc[mt][nt][r] + bb[nt]);
        const int h = (cq - 2 * NC) >> 6;
        u16* dst = vto + ((size_t)(b * HH + h) * 64 + l) * SS + srow;
#pragma unroll
        for (int c = 0; c < 8; c++)
            *(u16x8*)&dst[c * 8] = *(const u16x8*)&tw[l * 72 + c * 8];
    }
}

// ---------------- MFMA flash attention: S^T scheme, register PV ----------------
// grid (24, 4, 8): XCD = (h + 24*b) % 8 = h % 8 is pr-invariant => each XCD's
// 12 K/V streams (3MB) stay L2-resident across all 8 pr rounds.
// Block pr handles q-tiles (pr, 15-pr): exactly 17 k-iters; wave w: 16 q-rows.
// S^T = K*Q^T: C-layout col=lane&15=q, row=quad*4+r=key == A-layout of the
// 16x16x16 MFMA => P feeds PV straight from registers (no LDS round trip).
__global__ __launch_bounds__(256)
void attn_kernel(const u16* __restrict__ qb, const u16* __restrict__ kb,
                 const u16* __restrict__ vtb, const float* __restrict__ qg,
                 const float* __restrict__ kg, const float* __restrict__ invO,
                 u16* __restrict__ z) {
    const int h = blockIdx.x, b = blockIdx.y, pr = blockIdx.z;
    const int t = threadIdx.x, w = t >> 6, l = t & 63, lr = l & 15, lq = l >> 4;

    __shared__ u16 sK[2][64 * 64], sVT[2][64 * 64];

    const size_t bh = (size_t)(b * HH + h);
    const u16* Kb = kb + bh * SS * 64;
    const u16* Vt = vtb + bh * 64 * SS;
    const float* kgb = kg + bh * SS;

    const int src_row = l >> 3;
    const int cbs = (l & 7) ^ src_row;
    const int swz = lr & 7;

    auto stage = [&](int kt, int buf) {
#pragma unroll
        for (int i = 0; i < 2; i++) {
            int kc = w * 2 + i;            // wave-uniform LDS bases only
            int row = kc * 8 + src_row;
            async16(Kb + ((size_t)(kt * 64 + row)) * 64 + cbs * 8, sK[buf] + kc * 512);
            async16(Vt + (size_t)row * SS + kt * 64 + cbs * 8, sVT[buf] + kc * 512);
        }
    };

    stage(0, 0);
    int cur = 0;
#pragma unroll
    for (int sub = 0; sub < 2; sub++) {
        const int QT = sub ? (15 - pr) : pr;
        const int q0 = QT * 64 + w * 16;   // wave's 16 q-rows
        const u16* Qw = qb + (bh * SS + q0) * 64;
        bf16x8 aq0 = *(const bf16x8*)(Qw + (size_t)lr * 64 + lq * 8);
        bf16x8 aq1 = *(const bf16x8*)(Qw + (size_t)lr * 64 + 32 + lq * 8);
        const float qgr = qg[bh * SS + q0 + lr];   // q = lane&15

        f32x4 o[4] = {};
        float lacc = 0.f;

        for (int kt = 0; kt <= QT; kt++) {
            __syncthreads();               // buf[cur] drained; prev reads done
            if (kt < QT) stage(kt + 1, cur ^ 1);
            else if (sub == 0) stage(0, cur ^ 1);  // sub1 starts at kt=0
            const u16* K_ = sK[cur];
            const u16* V_ = sVT[cur];

            float4 kgv[4];                 // key gate: 4 consecutive keys/lane
#pragma unroll
            for (int nt = 0; nt < 4; nt++)
                kgv[nt] = *(const float4*)&kgb[kt * 64 + nt * 16 + lq * 4];

            // S^T = K Q^T: D[m=key][n=q]; lane: q=lr, keys=lq*4+r (per nt)
            f32x4 st[4] = {};
#pragma unroll
            for (int s = 0; s < 2; s++) {
                const int j8 = ((s * 4 + lq) ^ swz) * 8;
                const bf16x8 aqs = s ? aq1 : aq0;
#pragma unroll
                for (int nt = 0; nt < 4; nt++) {
                    bf16x8 bk = *(const bf16x8*)&K_[(nt * 16 + lr) * 64 + j8];
                    st[nt] = __builtin_amdgcn_mfma_f32_16x16x32_bf16(bk, aqs, st[nt], 0, 0, 0);
                }
            }

            const bool diag = (kt == QT);
            bf16x4 af[4];
#pragma unroll
            for (int nt = 0; nt < 4; nt++) {
#pragma unroll
                for (int r = 0; r < 4; r++) {
                    float pv = exp2f(st[nt][r]);   // log2e pre-folded into q
                    if (diag && (nt * 16 + lq * 4 + r > w * 16 + lr)) pv = 0.f;
                    lacc += pv;                    // l over UNGATED p
                    float g = fminf(fmaxf(qgr * ((const float*)&kgv[nt])[r], 0.f), 1.f);
                    af[nt][r] = (short)f2bf(pv * g);
                }
            }

            // O += P V: A = P from registers; B = V^T frag (ds_read_b64)
#pragma unroll
            for (int nt = 0; nt < 4; nt++) {
                const int vcol = (((nt * 2 + (lq >> 1)) ^ swz) << 3) + ((lq & 1) << 2);
#pragma unroll
                for (int dt = 0; dt < 4; dt++) {
                    bf16x4 vf = *(const bf16x4*)&V_[(dt * 16 + lr) * 64 + vcol];
                    o[dt] = __builtin_amdgcn_mfma_f32_16x16x16bf16_1k(af[nt], vf, o[dt], 0, 0, 0);
                }
            }
            cur ^= 1;
        }

        // l(q=lr): sum partials across the 4 lq groups
        float lv = lacc;
        lv += __shfl_xor(lv, 16);
        lv += __shfl_xor(lv, 32);
        const float linv = __builtin_amdgcn_rcpf(lv);
        float inv_r[4];                    // O rows are q=lq*4+r: fetch matching l
#pragma unroll
        for (int r = 0; r < 4; r++)
            inv_r[r] = __shfl(linv, (l & 48) | (lq * 4 + r));

        // epilogue: z = (o/l)*invO -> bf16 [B,S,1536]; O: col=d=lr, row=q=lq*4+r
        const int col0 = h * 64;
#pragma unroll
        for (int dt = 0; dt < 4; dt++) {
            float io = invO[col0 + dt * 16 + lr];
#pragma unroll
            for (int r = 0; r < 4; r++) {
                float val = o[dt][r] * inv_r[r] * io;
                z[((size_t)b * SS + q0 + lq * 4 + r) * NC + col0 + dt * 16 + lr] = f2bf(val);
            }
        }
    }
}

// ---------------- out MFMA GEMM: out[4096,768] = z[4096,1536] @ woT[d][j]^T ----------------
// 64x64 tiles, grid (12,64)=768 (3/CU exact), dbuf single-barrier staging.
__global__ __launch_bounds__(256)
void out_gemm_kernel(const u16* __restrict__ zb, const u16* __restrict__ woT,
                     float* __restrict__ out) {
    const int n0 = blockIdx.x * 64, row0 = blockIdx.y * 64;
    const int t = threadIdx.x, w = t >> 6, l = t & 63, lr = l & 15, lq = l >> 4;
    const int wr = (w >> 1) * 32, wc = (w & 1) * 32;
    __shared__ u16 sA[2][64 * 64], sB[2][64 * 64];

    const int src_row = l >> 3;
    const int cbs = (l & 7) ^ src_row;
    const int swz = lr & 7;

    auto stage = [&](int k0, int buf) {
#pragma unroll
        for (int i = 0; i < 2; i++) {
            int ch = w * 2 + i;
            int row = ch * 8 + src_row;
            async16(zb + (size_t)(row0 + row) * NC + k0 + cbs * 8, sA[buf] + ch * 512);
            async16(woT + (size_t)(n0 + row) * NC + k0 + cbs * 8, sB[buf] + ch * 512);
        }
    };

    stage(0, 0);
    int cur = 0;
    f32x4 acc[2][2] = {};
    for (int k0 = 0; k0 < NC; k0 += 64) {
        __syncthreads();
        if (k0 + 64 < NC) stage(k0 + 64, cur ^ 1);
#pragma unroll
        for (int s = 0; s < 2; s++) {
            const int j8 = ((s * 4 + lq) ^ swz) * 8;
            bf16x8 af[2], bf[2];
#pragma unroll
            for (int i = 0; i < 2; i++) {
                af[i] = *(const bf16x8*)&sA[cur][(wr + i * 16 + lr) * 64 + j8];
                bf[i] = *(const bf16x8*)&sB[cur][(wc + i * 16 + lr) * 64 + j8];
            }
#pragma unroll
            for (int mt = 0; mt < 2; mt++)
#pragma unroll
                for (int nt = 0; nt < 2; nt++)
                    acc[mt][nt] = __builtin_amdgcn_mfma_f32_16x16x32_bf16(
                        af[mt], bf[nt], acc[mt][nt], 0, 0, 0);
        }
        cur ^= 1;
    }
#pragma unroll
    for (int mt = 0; mt < 2; mt++)
#pragma unroll
        for (int nt = 0; nt < 2; nt++)
#pragma unroll
            for (int r = 0; r < 4; r++)
                out[(size_t)(row0 + wr + mt * 16 + lq * 4 + r) * DD + n0 + wc + nt * 16 + lr] =
                    acc[mt][nt][r];
}

}  // namespace

extern "C" void kernel_launch(void* const* d_in, const int* in_sizes, int n_in,
                              void* d_out, int out_size, void* d_ws, size_t ws_size,
                              hipStream_t stream) {
    const float* x   = (const float*)d_in[0];
    const float* W_Q = (const float*)d_in[1];
    const float* W_K = (const float*)d_in[2];
    const float* W_V = (const float*)d_in[3];
    const float* W_O = (const float*)d_in[4];
    const float* b_Q = (const float*)d_in[5];
    const float* b_K = (const float*)d_in[6];
    const float* b_V = (const float*)d_in[7];
    const float* Wgq = (const float*)d_in[8];
    const float* Wgk = (const float*)d_in[9];
    const float* bgq = (const float*)d_in[10];
    const float* bgk = (const float*)d_in[11];
    float* out = (float*)d_out;

    char* wsb = (char*)d_ws;
    auto alloc = [&](size_t bytes) -> char* {
        char* p = wsb;
        wsb += (bytes + 255) & ~(size_t)255;
        return p;
    };
    float* invV  = (float*)alloc((size_t)NC * 4);
    float* invO  = (float*)alloc((size_t)NC * 4);
    float* biasp = (float*)alloc((size_t)NQKV * 4);
    float* qg    = (float*)alloc((size_t)RR * HH * 4);
    float* kg    = (float*)alloc((size_t)RR * HH * 4);
    u16* xb      = (u16*)alloc((size_t)RR * DD * 2);
    u16* wT      = (u16*)alloc((size_t)NTOT * DD * 2);
    u16* woT     = (u16*)alloc((size_t)DD * NC * 2);
    u16* qb      = (u16*)alloc((size_t)RR * 64 * HH * 2);
    u16* kb      = (u16*)alloc((size_t)RR * 64 * HH * 2);
    u16* vtb     = (u16*)alloc((size_t)RR * 64 * HH * 2);
    u16* zb      = (u16*)alloc((size_t)RR * NC * 2);

    norms_kernel<<<NC, 256, 0, stream>>>(W_V, W_O, invV, invO);
    x2bf_kernel<<<RR * DD / 4 / 256, 256, 0, stream>>>(x, xb);
    pack_wqkv_kernel<<<dim3(DD / 64, HH, 3), 256, 0, stream>>>(W_Q, W_K, W_V, invV, wT);
    pack_gates_kernel<<<128, 256, 0, stream>>>(Wgq, Wgk, wT);
    pack_bias_kernel<<<(NQKV + 255) / 256, 256, 0, stream>>>(b_Q, b_K, b_V, biasp);
    pack_wo_kernel<<<dim3(NC / 64, DD / 64), 256, 0, stream>>>(W_O, woT);
    qkv_gemm_kernel<<<dim3(NTOT / 128, RR / 128), 256, 0, stream>>>(
        xb, wT, biasp, bgq, bgk, qb, kb, vtb, qg, kg);
    attn_kernel<<<dim3(HH, BB, 8), 256, 0, stream>>>(
        qb, kb, vtb, qg, kg, invO, zb);
    out_gemm_kernel<<<dim3(DD / 64, RR / 64), 256, 0, stream>>>(zb, woT, out);
}

// Round 10
// 231.613 us; speedup vs baseline: 1.0071x; 1.0071x over previous
//
#include <hip/hip_runtime.h>
#include <math.h>

// ModifiedAttention bf16-MFMA pipeline v9: B=4,S=1024,D=768,H=24,DH=64,DG=1
//  = v6 (last passing) with:
//   - attn: 128-row q-tiles (4 waves x 32 q-rows, 2 q-blocks/wave), S^T
//     register-PV scheme unchanged; heavy tiles dispatched first.
//   - pack_bias removed (qkv epilogue reads b_Q/b_K/b_V directly).
//  qkv K-loop: R6's proven two-barrier BK=64 (the BK=32 rework crashed in
//  R7/R8 with all other suspects reverted -- do not reintroduce).
//  (R9 was a GPU-acquisition timeout; this is the same source resubmitted.)

namespace {

typedef short bf16x8 __attribute__((ext_vector_type(8)));
typedef short bf16x4 __attribute__((ext_vector_type(4)));
typedef float f32x4 __attribute__((ext_vector_type(4)));
typedef unsigned short u16;
typedef u16 u16x8 __attribute__((ext_vector_type(8)));
typedef unsigned int u32;

constexpr int BB = 4, SS = 1024, DD = 768, HH = 24;
constexpr int RR = BB * SS;     // 4096
constexpr int NC = HH * 64;     // 1536
constexpr int NQKV = 3 * NC;    // 4608
constexpr int NTOT = NQKV + 128; // + gate block

__device__ inline u16 f2bf(float f) {   // RNE fp32 -> bf16
    u32 u = __float_as_uint(f);
    u += 0x7FFFu + ((u >> 16) & 1u);
    return (u16)(u >> 16);
}

// async global->LDS, 16B/lane; LDS base MUST be wave-uniform (HW scatters lane*16)
__device__ __forceinline__ void async16(const void* g, const void* lds) {
    __builtin_amdgcn_global_load_lds(
        (const __attribute__((address_space(1))) u32*)(unsigned long long)(size_t)g,
        (__attribute__((address_space(3))) u32*)(u32)(size_t)lds, 16, 0, 0);
}

// ---------------- weight column/row inverse norms ----------------
__global__ __launch_bounds__(256)
void norms_kernel(const float* __restrict__ Wv, const float* __restrict__ Wo,
                  float* __restrict__ invV, float* __restrict__ invO) {
    int j = blockIdx.x;            // (h,dh) flat, 1536
    int h = j >> 6, dh = j & 63;
    __shared__ float sv[256], so[256];
    float av = 0.f, ao = 0.f;
    for (int d = threadIdx.x; d < DD; d += 256) {
        float a = Wv[(h * DD + d) * 64 + dh];    // W_V[h,d,dh], norm over d
        av += a * a;
        float b = Wo[(size_t)j * DD + d];        // W_O[h,dh,d], norm over d
        ao += b * b;
    }
    sv[threadIdx.x] = av; so[threadIdx.x] = ao;
    __syncthreads();
    for (int s = 128; s > 0; s >>= 1) {
        if (threadIdx.x < s) {
            sv[threadIdx.x] += sv[threadIdx.x + s];
            so[threadIdx.x] += so[threadIdx.x + s];
        }
        __syncthreads();
    }
    if (threadIdx.x == 0) {
        invV[j] = 1.f / fmaxf(sqrtf(sv[0]), 1e-12f);
        invO[j] = 1.f / fmaxf(sqrtf(so[0]), 1e-12f);
    }
}

// ---------------- x -> bf16 ----------------
__global__ __launch_bounds__(256)
void x2bf_kernel(const float* __restrict__ x, u16* __restrict__ xb) {
    int idx = blockIdx.x * 256 + threadIdx.x;       // RR*DD/4 float4s
    float4 v = ((const float4*)x)[idx];
    ushort4 o;
    o.x = f2bf(v.x); o.y = f2bf(v.y); o.z = f2bf(v.z); o.w = f2bf(v.w);
    ((ushort4*)xb)[idx] = o;
}

// ---------------- pack W_{Q,K,V} -> wT rows [0,4608) x 768 bf16 ----------------
__global__ __launch_bounds__(256)
void pack_wqkv_kernel(const float* __restrict__ Wq, const float* __restrict__ Wk,
                      const float* __restrict__ Wv, const float* __restrict__ invV,
                      u16* __restrict__ wT) {
    const int k0 = blockIdx.x * 64, h = blockIdx.y, p = blockIdx.z;
    const float* W = (p == 0 ? Wq : p == 1 ? Wk : Wv) + (size_t)h * DD * 64;
    __shared__ float sT[64][68];
    const int t = threadIdx.x;
#pragma unroll
    for (int rep = 0; rep < 4; rep++) {
        int idx = t + rep * 256; int kk = idx >> 4, c = idx & 15;
        *(float4*)&sT[kk][c * 4] = *(const float4*)&W[(size_t)(k0 + kk) * 64 + c * 4];
    }
    __syncthreads();
#pragma unroll
    for (int rep = 0; rep < 2; rep++) {
        int idx = t + rep * 256; int dh = idx >> 3, cj = idx & 7;
        float sc = (p == 2) ? invV[h * 64 + dh] : 1.f;
        u16x8 o;
#pragma unroll
        for (int i = 0; i < 8; i++) o[i] = f2bf(sT[cj * 8 + i][dh] * sc);
        *(u16x8*)&wT[(size_t)(p * NC + h * 64 + dh) * DD + k0 + cj * 8] = o;
    }
}

// ---------------- pack gate weights -> wT rows [4608,4736) ----------------
__global__ __launch_bounds__(256)
void pack_gates_kernel(const float* __restrict__ Wgq, const float* __restrict__ Wgk,
                       u16* __restrict__ wT) {
    int g = blockIdx.x;           // 0..127
    u16* dst = wT + (size_t)(NQKV + g) * DD;
    if (g < 48) {
        const float* src = ((g & 1) ? Wgk : Wgq) + (size_t)(g >> 1) * DD;
        for (int c = threadIdx.x; c < DD; c += 256) dst[c] = f2bf(src[c]);
    } else {
        for (int c = threadIdx.x; c < DD; c += 256) dst[c] = 0;
    }
}

// ---------------- pack W_O -> woT [768 d][1536 j] bf16 ----------------
__global__ __launch_bounds__(256)
void pack_wo_kernel(const float* __restrict__ Wo, u16* __restrict__ woT) {
    const int j0 = blockIdx.x * 64, d0 = blockIdx.y * 64;
    __shared__ float sT[64][68];
    const int t = threadIdx.x;
#pragma unroll
    for (int rep = 0; rep < 4; rep++) {
        int idx = t + rep * 256; int jj = idx >> 4, c = idx & 15;
        *(float4*)&sT[jj][c * 4] = *(const float4*)&Wo[(size_t)(j0 + jj) * DD + d0 + c * 4];
    }
    __syncthreads();
#pragma unroll
    for (int rep = 0; rep < 2; rep++) {
        int idx = t + rep * 256; int dd = idx >> 3, cj = idx & 7;
        u16x8 o;
#pragma unroll
        for (int i = 0; i < 8; i++) o[i] = f2bf(sT[cj * 8 + i][dd]);
        *(u16x8*)&woT[(size_t)(d0 + dd) * NC + j0 + cj * 8] = o;
    }
}

// ---------------- qkv+gates MFMA GEMM: C[4096,4736] = xb @ wT^T ----------------
// Supertile swizzle (wT L2 reuse); R6 two-barrier BK=64 K-loop (proven).
__global__ __launch_bounds__(256)
void qkv_gemm_kernel(const u16* __restrict__ xb, const u16* __restrict__ wT,
                     const float* __restrict__ bq, const float* __restrict__ bk,
                     const float* __restrict__ bv,
                     const float* __restrict__ bgq, const float* __restrict__ bgk,
                     u16* __restrict__ qo, u16* __restrict__ ko, u16* __restrict__ vto,
                     float* __restrict__ qgo, float* __restrict__ kgo) {
    const int flat = blockIdx.x + 37 * blockIdx.y;
    const int grp = flat / 296;            // 296 = 8 m-tiles * 37 n-tiles
    const int rem = flat - grp * 296;
    const int row0 = (grp * 8 + (rem & 7)) * 128;
    const int n0 = (rem >> 3) * 128;
    const int t = threadIdx.x, w = t >> 6, l = t & 63, lr = l & 15, lq = l >> 4;
    const int wr = (w >> 1) * 64, wc = (w & 1) * 64;
    __shared__ u16 smem[4 * 4608];   // main: sA 16KB | sB 16KB; epi: 4x 64x72
    u16* sA = smem;
    u16* sB = smem + 8192;

    const int src_row = l >> 3;            // 0..7 within 8-row chunk
    const int cbs = (l & 7) ^ src_row;     // swizzled source col-block
    const int swz = lr & 7;                // read-side swizzle

    f32x4 acc[4][4] = {};
    for (int k0 = 0; k0 < DD; k0 += 64) {
        __syncthreads();
#pragma unroll
        for (int i = 0; i < 4; i++) {
            int ch = w * 4 + i;            // 16 chunks of 8 rows each
            int rowA = ch * 8 + src_row;
            async16(xb + (size_t)(row0 + rowA) * DD + k0 + cbs * 8, sA + ch * 512);
            async16(wT + (size_t)(n0 + rowA) * DD + k0 + cbs * 8, sB + ch * 512);
        }
        __syncthreads();
#pragma unroll
        for (int s = 0; s < 2; s++) {
            const int j8 = ((s * 4 + lq) ^ swz) * 8;
            bf16x8 af[4], bf[4];
#pragma unroll
            for (int i = 0; i < 4; i++) {
                af[i] = *(const bf16x8*)&sA[(wr + i * 16 + lr) * 64 + j8];
                bf[i] = *(const bf16x8*)&sB[(wc + i * 16 + lr) * 64 + j8];
            }
#pragma unroll
            for (int mt = 0; mt < 4; mt++)
#pragma unroll
                for (int nt = 0; nt < 4; nt++)
                    acc[mt][nt] = __builtin_amdgcn_mfma_f32_16x16x32_bf16(
                        af[mt], bf[nt], acc[mt][nt], 0, 0, 0);
        }
    }
    __syncthreads();                       // frag reads done before LDS reuse

    const int p = n0 / NC;                 // 0..3 (3 = gate block)
    const int b = row0 >> 10, s0 = row0 & (SS - 1);

    if (p == 3) {                          // gates: cols j = nt*16+lr < 48
        if (wc == 0) {
#pragma unroll
            for (int nt = 0; nt < 3; nt++) {
                int j = nt * 16 + lr, hh = j >> 1;
                float bias = (j & 1) ? bgk[hh] : bgq[hh];
                float* dst = (j & 1) ? kgo : qgo;
#pragma unroll
                for (int mt = 0; mt < 4; mt++)
#pragma unroll
                    for (int r = 0; r < 4; r++)
                        dst[((size_t)b * HH + hh) * SS + s0 + wr + mt * 16 + lq * 4 + r] =
                            acc[mt][nt][r] + bias;
            }
        }
        return;
    }

    const int cq = n0 + wc, srow = s0 + wr;
    u16* tw = smem + w * 4608;             // per-wave 64 x 72 region
    const float* bias = (p == 0) ? bq : (p == 1) ? bk : bv;
    float bb[4];
#pragma unroll
    for (int nt = 0; nt < 4; nt++) bb[nt] = bias[cq - p * NC + nt * 16 + lr];

    if (p < 2) {                           // q or k: layout [s][dh]
        // q: fold 1/sqrt(64) * log2(e) so attention uses raw exp2
        const float sc = (p == 0) ? 0.18033688f : 1.f;
#pragma unroll
        for (int mt = 0; mt < 4; mt++)
#pragma unroll
            for (int nt = 0; nt < 4; nt++)
#pragma unroll
                for (int r = 0; r < 4; r++)
                    tw[(mt * 16 + lq * 4 + r) * 72 + nt * 16 + lr] =
                        f2bf((acc[mt][nt][r] + bb[nt]) * sc);
        const int h = (cq - p * NC) >> 6;
        u16* dst = (p == 0 ? qo : ko) + ((size_t)(b * HH + h) * SS + srow) * 64;
#pragma unroll
        for (int c = 0; c < 8; c++)
            *(u16x8*)&dst[(size_t)l * 64 + c * 8] = *(const u16x8*)&tw[l * 72 + c * 8];
    } else {                               // v: transpose to [dh][s]
#pragma unroll
        for (int mt = 0; mt < 4; mt++)
#pragma unroll
            for (int nt = 0; nt < 4; nt++)
#pragma unroll
                for (int r = 0; r < 4; r++)
                    tw[(nt * 16 + lr) * 72 + mt * 16 + lq * 4 + r] =
                        f2bf(acc[mt][nt][r] + bb[nt]);
        const int h = (cq - 2 * NC) >> 6;
        u16* dst = vto + ((size_t)(b * HH + h) * 64 + l) * SS + srow;
#pragma unroll
        for (int c = 0; c < 8; c++)
            *(u16x8*)&dst[c * 8] = *(const u16x8*)&tw[l * 72 + c * 8];
    }
}

// ---------------- MFMA flash attention: S^T scheme, register PV, 128-row tiles ----------------
// grid (24, 4, 8): XCD = h % 8 (tile-invariant, K/V L2-resident). tile =
// 7 - blockIdx.z so heavy tiles dispatch first. Wave w owns 32 q-rows
// (2 q-blocks of 16); K/V staged as 64-key tiles, single-barrier dbuf.
// S^T = K*Q^T: C-layout col=lane&15=q, row=quad*4+r=key == A-layout of the
// 16x16x16 MFMA => P feeds PV straight from registers (no LDS round trip).
__global__ __launch_bounds__(256)
void attn_kernel(const u16* __restrict__ qb, const u16* __restrict__ kb,
                 const u16* __restrict__ vtb, const float* __restrict__ qg,
                 const float* __restrict__ kg, const float* __restrict__ invO,
                 u16* __restrict__ z) {
    const int h = blockIdx.x, b = blockIdx.y;
    const int tile = 7 - blockIdx.z;       // heavy first
    const int t = threadIdx.x, w = t >> 6, l = t & 63, lr = l & 15, lq = l >> 4;

    __shared__ u16 sK[2][64 * 64], sVT[2][64 * 64];

    const size_t bh = (size_t)(b * HH + h);
    const u16* Kb = kb + bh * SS * 64;
    const u16* Vt = vtb + bh * 64 * SS;
    const float* kgb = kg + bh * SS;

    const int src_row = l >> 3;
    const int cbs = (l & 7) ^ src_row;
    const int swz = lr & 7;

    auto stage = [&](int kt, int buf) {
#pragma unroll
        for (int i = 0; i < 2; i++) {
            int kc = w * 2 + i;            // wave-uniform LDS bases only
            int row = kc * 8 + src_row;
            async16(Kb + ((size_t)(kt * 64 + row)) * 64 + cbs * 8, sK[buf] + kc * 512);
            async16(Vt + (size_t)row * SS + kt * 64 + cbs * 8, sVT[buf] + kc * 512);
        }
    };

    const int q0w = tile * 128 + w * 32;   // wave's 32 q-rows
    const u16* Qw = qb + (bh * SS + q0w) * 64;
    bf16x8 aq[2][2];
#pragma unroll
    for (int qi = 0; qi < 2; qi++)
#pragma unroll
        for (int s = 0; s < 2; s++)
            aq[qi][s] = *(const bf16x8*)(Qw + (size_t)(qi * 16 + lr) * 64 + s * 32 + lq * 8);
    float qgr[2];
#pragma unroll
    for (int qi = 0; qi < 2; qi++) qgr[qi] = qg[bh * SS + q0w + qi * 16 + lr];

    f32x4 o[2][4] = {};
    float lacc[2] = {0.f, 0.f};

    const int ktmax = 2 * tile + 1;
    stage(0, 0);
    int cur = 0;
    for (int kt = 0; kt <= ktmax; kt++) {
        __syncthreads();                   // buf[cur] drained; prev reads done
        if (kt < ktmax) stage(kt + 1, cur ^ 1);
        const u16* K_ = sK[cur];
        const u16* V_ = sVT[cur];

        if (kt * 64 < q0w + 32) {          // wave-uniform: any unmasked keys
            float4 kgv[4];                 // key gate: 4 consecutive keys/lane
#pragma unroll
            for (int nt = 0; nt < 4; nt++)
                kgv[nt] = *(const float4*)&kgb[kt * 64 + nt * 16 + lq * 4];

            // S^T = K Q^T: D[m=key][n=q]; lane: q=lr, keys=lq*4+r (per nt)
            f32x4 st[2][4] = {};
#pragma unroll
            for (int s = 0; s < 2; s++) {
                const int j8 = ((s * 4 + lq) ^ swz) * 8;
#pragma unroll
                for (int nt = 0; nt < 4; nt++) {
                    bf16x8 bk = *(const bf16x8*)&K_[(nt * 16 + lr) * 64 + j8];
#pragma unroll
                    for (int qi = 0; qi < 2; qi++)
                        st[qi][nt] = __builtin_amdgcn_mfma_f32_16x16x32_bf16(
                            bk, aq[qi][s], st[qi][nt], 0, 0, 0);
                }
            }

            bf16x4 af[2][4];
#pragma unroll
            for (int qi = 0; qi < 2; qi++) {
                const bool need_mask = (kt * 64 + 63 > q0w + qi * 16);
#pragma unroll
                for (int nt = 0; nt < 4; nt++) {
#pragma unroll
                    for (int r = 0; r < 4; r++) {
                        float pv = exp2f(st[qi][nt][r]);   // log2e folded into q
                        if (need_mask &&
                            (kt * 64 + nt * 16 + lq * 4 + r > q0w + qi * 16 + lr))
                            pv = 0.f;
                        lacc[qi] += pv;                    // l over UNGATED p
                        float g = fminf(fmaxf(qgr[qi] * ((const float*)&kgv[nt])[r],
                                              0.f), 1.f);
                        af[qi][nt][r] = (short)f2bf(pv * g);
                    }
                }
            }

            // O += P V: A = P from registers; B = V^T frag (shared across qi)
#pragma unroll
            for (int nt = 0; nt < 4; nt++) {
                const int vcol = (((nt * 2 + (lq >> 1)) ^ swz) << 3) + ((lq & 1) << 2);
#pragma unroll
                for (int dt = 0; dt < 4; dt++) {
                    bf16x4 vf = *(const bf16x4*)&V_[(dt * 16 + lr) * 64 + vcol];
#pragma unroll
                    for (int qi = 0; qi < 2; qi++)
                        o[qi][dt] = __builtin_amdgcn_mfma_f32_16x16x16bf16_1k(
                            af[qi][nt], vf, o[qi][dt], 0, 0, 0);
                }
            }
        }
        cur ^= 1;
    }

    // per q-block: reduce l across lq groups, then epilogue
    const int col0 = h * 64;
#pragma unroll
    for (int qi = 0; qi < 2; qi++) {
        float lv = lacc[qi];
        lv += __shfl_xor(lv, 16);
        lv += __shfl_xor(lv, 32);
        const float linv = __builtin_amdgcn_rcpf(lv);
        float inv_r[4];                    // O rows are q=lq*4+r: fetch matching l
#pragma unroll
        for (int r = 0; r < 4; r++)
            inv_r[r] = __shfl(linv, (l & 48) | (lq * 4 + r));
#pragma unroll
        for (int dt = 0; dt < 4; dt++) {
            float io = invO[col0 + dt * 16 + lr];
#pragma unroll
            for (int r = 0; r < 4; r++) {
                float val = o[qi][dt][r] * inv_r[r] * io;
                z[((size_t)b * SS + q0w + qi * 16 + lq * 4 + r) * NC + col0 + dt * 16 + lr] =
                    f2bf(val);
            }
        }
    }
}

// ---------------- out MFMA GEMM: out[4096,768] = z[4096,1536] @ woT[d][j]^T ----------------
// 64x64 tiles, grid (12,64)=768 (3/CU exact), dbuf single-barrier staging.
__global__ __launch_bounds__(256)
void out_gemm_kernel(const u16* __restrict__ zb, const u16* __restrict__ woT,
                     float* __restrict__ out) {
    const int n0 = blockIdx.x * 64, row0 = blockIdx.y * 64;
    const int t = threadIdx.x, w = t >> 6, l = t & 63, lr = l & 15, lq = l >> 4;
    const int wr = (w >> 1) * 32, wc = (w & 1) * 32;
    __shared__ u16 sA[2][64 * 64], sB[2][64 * 64];

    const int src_row = l >> 3;
    const int cbs = (l & 7) ^ src_row;
    const int swz = lr & 7;

    auto stage = [&](int k0, int buf) {
#pragma unroll
        for (int i = 0; i < 2; i++) {
            int ch = w * 2 + i;
            int row = ch * 8 + src_row;
            async16(zb + (size_t)(row0 + row) * NC + k0 + cbs * 8, sA[buf] + ch * 512);
            async16(woT + (size_t)(n0 + row) * NC + k0 + cbs * 8, sB[buf] + ch * 512);
        }
    };

    stage(0, 0);
    int cur = 0;
    f32x4 acc[2][2] = {};
    for (int k0 = 0; k0 < NC; k0 += 64) {
        __syncthreads();
        if (k0 + 64 < NC) stage(k0 + 64, cur ^ 1);
#pragma unroll
        for (int s = 0; s < 2; s++) {
            const int j8 = ((s * 4 + lq) ^ swz) * 8;
            bf16x8 af[2], bf[2];
#pragma unroll
            for (int i = 0; i < 2; i++) {
                af[i] = *(const bf16x8*)&sA[cur][(wr + i * 16 + lr) * 64 + j8];
                bf[i] = *(const bf16x8*)&sB[cur][(wc + i * 16 + lr) * 64 + j8];
            }
#pragma unroll
            for (int mt = 0; mt < 2; mt++)
#pragma unroll
                for (int nt = 0; nt < 2; nt++)
                    acc[mt][nt] = __builtin_amdgcn_mfma_f32_16x16x32_bf16(
                        af[mt], bf[nt], acc[mt][nt], 0, 0, 0);
        }
        cur ^= 1;
    }
#pragma unroll
    for (int mt = 0; mt < 2; mt++)
#pragma unroll
        for (int nt = 0; nt < 2; nt++)
#pragma unroll
            for (int r = 0; r < 4; r++)
                out[(size_t)(row0 + wr + mt * 16 + lq * 4 + r) * DD + n0 + wc + nt * 16 + lr] =
                    acc[mt][nt][r];
}

}  // namespace

extern "C" void kernel_launch(void* const* d_in, const int* in_sizes, int n_in,
                              void* d_out, int out_size, void* d_ws, size_t ws_size,
                              hipStream_t stream) {
    const float* x   = (const float*)d_in[0];
    const float* W_Q = (const float*)d_in[1];
    const float* W_K = (const float*)d_in[2];
    const float* W_V = (const float*)d_in[3];
    const float* W_O = (const float*)d_in[4];
    const float* b_Q = (const float*)d_in[5];
    const float* b_K = (const float*)d_in[6];
    const float* b_V = (const float*)d_in[7];
    const float* Wgq = (const float*)d_in[8];
    const float* Wgk = (const float*)d_in[9];
    const float* bgq = (const float*)d_in[10];
    const float* bgk = (const float*)d_in[11];
    float* out = (float*)d_out;

    char* wsb = (char*)d_ws;
    auto alloc = [&](size_t bytes) -> char* {
        char* p = wsb;
        wsb += (bytes + 255) & ~(size_t)255;
        return p;
    };
    float* invV  = (float*)alloc((size_t)NC * 4);
    float* invO  = (float*)alloc((size_t)NC * 4);
    float* qg    = (float*)alloc((size_t)RR * HH * 4);
    float* kg    = (float*)alloc((size_t)RR * HH * 4);
    u16* xb      = (u16*)alloc((size_t)RR * DD * 2);
    u16* wT      = (u16*)alloc((size_t)NTOT * DD * 2);
    u16* woT     = (u16*)alloc((size_t)DD * NC * 2);
    u16* qb      = (u16*)alloc((size_t)RR * 64 * HH * 2);
    u16* kb      = (u16*)alloc((size_t)RR * 64 * HH * 2);
    u16* vtb     = (u16*)alloc((size_t)RR * 64 * HH * 2);
    u16* zb      = (u16*)alloc((size_t)RR * NC * 2);

    norms_kernel<<<NC, 256, 0, stream>>>(W_V, W_O, invV, invO);
    x2bf_kernel<<<RR * DD / 4 / 256, 256, 0, stream>>>(x, xb);
    pack_wqkv_kernel<<<dim3(DD / 64, HH, 3), 256, 0, stream>>>(W_Q, W_K, W_V, invV, wT);
    pack_gates_kernel<<<128, 256, 0, stream>>>(Wgq, Wgk, wT);
    pack_wo_kernel<<<dim3(NC / 64, DD / 64), 256, 0, stream>>>(W_O, woT);
    qkv_gemm_kernel<<<dim3(NTOT / 128, RR / 128), 256, 0, stream>>>(
        xb, wT, b_Q, b_K, b_V, bgq, bgk, qb, kb, vtb, qg, kg);
    attn_kernel<<<dim3(HH, BB, 8), 256, 0, stream>>>(
        qb, kb, vtb, qg, kg, invO, zb);
    out_gemm_kernel<<<dim3(DD / 64, RR / 64), 256, 0, stream>>>(zb, woT, out);
}